// Round 9
// baseline (712.613 us; speedup 1.0000x reference)
//
#include <hip/hip_runtime.h>

// ExtractSearchWindows: out[b,h,w,rr,tt] = (uint8)Q[b, h+off+ry+ty, w+off+rx+tx],
// Q = input padded by 6; stored as INT32 (harness reads uint8 ref via int32 path).
// R8 post-mortem / accounting fix: dur = ~567us fixed harness poison fills
// (2.83GB d_ws @454us + 708MB d_out @113us) + kernel. Kernel is ~139us = 5.1TB/s
// (82% of fill's 6.24TB/s), which is why six structural variants tied.
// R9 = exact fill-mimicry: whole padded batch image in LDS as u8 (204^2 = 41.6KB
// + 4.8KB tbl -> 2 blocks/CU, 32 waves/CU); output decomposed into flat 4KB
// chunks, chunk c = bid + it*256 per batch -> 2MB chip-wide sweeping window,
// every wave span 1KB-aligned, blocks in lockstep = the fill's address stream.
// Decode: one magic-div by d (Granlund-Montgomery, M=ceil(2^45/d), J*d < 2^40)
// + compile-time const divs. 4x ds_read_u8 + 1 aligned dwordx4 store per quad.

#define KT 7
#define K2 49
#define MAX_SR 3
#define B_ 2
#define H_ 192
#define W_ 192
#define HW (H_ * W_)        // 36864
#define PAD 6
#define PY 204              // padded image dim (192 + 2*6)
#define PIMG (PY * PY)      // 41616 bytes as u8
#define NTHREADS 1024
#define NB 512              // 2 blocks/CU; bids 0..255 -> batch 0, 256..511 -> batch 1

typedef int vint4 __attribute__((ext_vector_type(4)));

__global__ __launch_bounds__(NTHREADS) void esw_kernel(
    const float* __restrict__ in, int* __restrict__ out,
    int cv, int offset, int d /* cv*cv*49 */, unsigned long long M /* ceil(2^45/d) */)
{
    __shared__ unsigned char pimg[PIMG];      // padded batch image, u8
    __shared__ unsigned short tbl[K2 * K2];   // tbl[j] = dy_*204 + dx_  (<= 2460)

    const int tid = threadIdx.x;
    const int bid = blockIdx.x;
    const int batch = bid >> 8;

    // Stage this batch's padded image as u8 (uint8 trunc applied; vals in [0,255)).
    const float* inb = in + batch * HW;
    for (int i = tid; i < PIMG; i += NTHREADS) {
        int y = i / PY;                       // const divisor
        int x = i - y * PY;
        int yy = y - PAD, xx = x - PAD;
        unsigned char v = 0;
        if ((unsigned)yy < (unsigned)H_ && (unsigned)xx < (unsigned)W_)
            v = (unsigned char)(int)inb[yy * W_ + xx];
        pimg[i] = v;
    }
    // Pixel-independent template table.
    for (int j = tid; j < d; j += NTHREADS) {
        int rr = j / K2;                      // const divisor 49
        int tt = j - rr * K2;
        int ry = rr / cv;                     // runtime div, setup only
        int rx = rr - ry * cv;
        int ty = tt / KT;                     // const divisor 7
        int tx = tt - ty * KT;
        tbl[j] = (unsigned short)((offset + ry + ty) * PY + (offset + rx + tx));
    }
    __syncthreads();

    // Flat 4KB chunks: per batch nchunk = HW*d/1024 = 9*d (exact). Chunk c is
    // dwords [gc*1024, gc*1024+1024) of out, gc = batch*9d + c. Wave spans are
    // 1KB-aligned; 256 blocks per batch sweep in lockstep (2MB window).
    const int nchunk = 9 * d;
    const unsigned cb = (unsigned)batch * (unsigned)nchunk;
    const int bathw = batch * HW;
    for (unsigned c = (unsigned)(bid & 255); c < (unsigned)nchunk; c += 256u) {
        unsigned J = ((cb + c) << 12) + 4u * (unsigned)tid;   // global dword idx
        unsigned p = (unsigned)(((unsigned long long)J * M) >> 45);  // J / d
        int j = (int)(J - p * (unsigned)d);
        int pr = (int)p - bathw;              // pixel within batch (always valid)
        int h = pr / W_;                      // const divisor 192
        int w = pr - h * W_;
        int base = h * PY + w;
        if (j + 3 < d) {                      // quad within one pixel's run
            vint4 v;
            v.x = (int)pimg[base + tbl[j]];
            v.y = (int)pimg[base + tbl[j + 1]];
            v.z = (int)pimg[base + tbl[j + 2]];
            v.w = (int)pimg[base + tbl[j + 3]];
            *(vint4*)(out + J) = v;           // 1KB wave span, 128B-aligned
        } else {                              // pixel boundary inside quad (rare)
            #pragma unroll
            for (int u = 0; u < 4; ++u) {
                int jj = j + u, pr2 = pr;
                if (jj >= d) { jj -= d; ++pr2; }   // next pixel, same batch
                int h2 = pr2 / W_;            // const divisor
                int w2 = pr2 - h2 * W_;
                out[J + u] = (int)pimg[h2 * PY + w2 + tbl[jj]];
            }
        }
    }
}

extern "C" void kernel_launch(void* const* d_in, const int* in_sizes, int n_in,
                              void* d_out, int out_size, void* d_ws, size_t ws_size,
                              hipStream_t stream) {
    const float* in = (const float*)d_in[0];
    int* out = (int*)d_out;

    // out_size = B*H*W * cv^2 * 49
    int cv2 = out_size / (B_ * H_ * W_ * K2);
    int cv = 1;
    while (cv * cv < cv2) ++cv;
    int offset = MAX_SR - (cv - 1) / 2;
    int d = cv2 * K2;
    unsigned long long M = ((1ULL << 45) + (unsigned long long)d - 1) / (unsigned long long)d;

    esw_kernel<<<NB, NTHREADS, 0, stream>>>(in, out, cv, offset, d, M);
}